// Round 8
// baseline (122.893 us; speedup 1.0000x reference)
//
#include <hip/hip_runtime.h>
#include <hip/hip_bf16.h>
#include <hip/hip_cooperative_groups.h>

namespace cg = cooperative_groups;

// Problem constants (fixed by setup_inputs)
#define NB 8
#define G  2048
#define C  512
#define CH 8
#define NM 4
#define HD 10
#define NS 10
#define L1 1022
#define L2 509
#define L3 253
#define L4 125
#define CPAD 516  // C + 4 pad

// ================= fused cooperative kernel =================
// 512 blocks x 256 threads (2 blocks/CU, co-resident).
// Phase 1: density+datarepr (all 512 blocks)  -> d_out
// Phase 2: conv1..4 stencil tiles (200 blocks) -> ws_h4
// Phase 3: pool+linear+softmax+gumbel (8 blocks) -> d_out
__global__ __launch_bounds__(256) void k_fused(
    const float* __restrict__ xc, const float* __restrict__ yc,
    const float* __restrict__ xg, const float* __restrict__ logls,
    const float* __restrict__ w1, const float* __restrict__ b1,
    const float* __restrict__ w2, const float* __restrict__ b2,
    const float* __restrict__ w3, const float* __restrict__ b3,
    const float* __restrict__ w4, const float* __restrict__ b4,
    const float* __restrict__ wl, const float* __restrict__ bl,
    const float* __restrict__ unif,
    float* __restrict__ out_den, float* __restrict__ out_rep,
    float* __restrict__ out_mw,  float* __restrict__ out_ms,
    float* __restrict__ ws_h4)
{
    __shared__ __align__(16) float smem[2 * CH * CPAD];   // 8256 floats, 33 KB
    cg::grid_group grid = cg::this_grid();
    const int tid = threadIdx.x;

    // ---------------- Phase 1: density ----------------
    {
        float* sx = smem;
        float* sy = smem + CH * CPAD;
        const int b  = blockIdx.x >> 6;
        const int gt = blockIdx.x & 63;

        const float* xcb = xc + b * C * CH;
        const float* ycb = yc + b * C * CH;
        for (int i = tid; i < C * CH; i += 256) {
            const int c = i >> 3, H = i & 7;
            sx[H * CPAD + c] = xcb[i];
            sy[H * CPAD + c] = ycb[i];
        }
        __syncthreads();

        const int H  = tid & 7;
        const int gl = tid >> 3;
        const int g  = gt * 32 + gl;

        const float x = xg[(b * G + g) * CH + H];
        const float coef = -0.72134752044448170f * __expf(-2.0f * logls[H]);

        const float4* sxv = (const float4*)(sx + H * CPAD);
        const float4* syv = (const float4*)(sy + H * CPAD);

        float den = 0.0f, num = 0.0f;
        #pragma unroll 4
        for (int c4 = 0; c4 < C / 4; ++c4) {
            const float4 xv = sxv[c4];
            const float4 yv = syv[c4];
            #define STEP(XX, YY)                              \
            {                                                 \
                const float d = x - (XX);                     \
                const float w = exp2f((d * coef) * d);        \
                den += w; num = fmaf(w, (YY), num);           \
            }
            STEP(xv.x, yv.x) STEP(xv.y, yv.y) STEP(xv.z, yv.z) STEP(xv.w, yv.w)
            #undef STEP
        }

        const int o = (b * G + g) * CH + H;
        out_den[o] = den;
        out_rep[o] = num / (den + 1e-4f);
    }

    grid.sync();

    // ---------------- Phase 2: conv1..4 tiles ----------------
    if (blockIdx.x < NB * 25) {
        float* sxt = smem;          // 1000  [ci][125]
        float* sw1 = smem + 1000;   // 400   [k][ci][o]
        float* sw2 = smem + 1400;   // 500
        float* sw3 = smem + 1900;   // 500
        float* sw4 = smem + 2400;   // 500
        float* s1  = smem + 2900;   // 610   [ci][61]
        float* s2  = smem + 3510;   // 290
        float* s3  = smem + 3800;   // 130
        const int b = blockIdx.x / 25;
        const int t = blockIdx.x % 25;

        __syncthreads();   // phase-1 smem reads are done before overwrite
        {
            const float* src = out_rep + (b * G + 80 * t) * CH;
            for (int i = tid; i < 125 * CH; i += 256) {
                const int gl = i >> 3, ci = i & 7;
                sxt[ci * 125 + gl] = src[i];
            }
        }
        for (int i = tid; i < HD * CH * 5; i += 256) {
            const int o = i / 40, ci = (i / 5) % 8, k = i % 5;
            sw1[(k * CH + ci) * HD + o] = w1[i];
        }
        for (int i = tid; i < HD * HD * 5; i += 256) {
            const int o = i / 50, ci = (i / 5) % 10, k = i % 5;
            sw2[(k * HD + ci) * HD + o] = w2[i];
            sw3[(k * HD + ci) * HD + o] = w3[i];
            sw4[(k * HD + ci) * HD + o] = w4[i];
        }
        __syncthreads();

        for (int i = tid; i < 61 * HD; i += 256) {
            const int o = i % HD, ll = i / HD;
            float acc = b1[o];
            #pragma unroll
            for (int k = 0; k < 5; ++k)
                #pragma unroll
                for (int ci = 0; ci < CH; ++ci)
                    acc = fmaf(sxt[ci * 125 + 2 * ll + k], sw1[(k * CH + ci) * HD + o], acc);
            s1[o * 61 + ll] = fmaxf(acc, 0.0f);
        }
        __syncthreads();

        for (int i = tid; i < 29 * HD; i += 256) {
            const int o = i % HD, ll = i / HD;
            float acc = b2[o];
            #pragma unroll
            for (int k = 0; k < 5; ++k)
                #pragma unroll
                for (int ci = 0; ci < HD; ++ci)
                    acc = fmaf(s1[ci * 61 + 2 * ll + k], sw2[(k * HD + ci) * HD + o], acc);
            s2[o * 29 + ll] = fmaxf(acc, 0.0f);
        }
        __syncthreads();

        for (int i = tid; i < 13 * HD; i += 256) {
            const int o = i % HD, ll = i / HD;
            float acc = b3[o];
            #pragma unroll
            for (int k = 0; k < 5; ++k)
                #pragma unroll
                for (int ci = 0; ci < HD; ++ci)
                    acc = fmaf(s2[ci * 29 + 2 * ll + k], sw3[(k * HD + ci) * HD + o], acc);
            s3[o * 13 + ll] = fmaxf(acc, 0.0f);
        }
        __syncthreads();

        for (int i = tid; i < 5 * HD; i += 256) {
            const int o = i % HD, ll = i / HD;
            float acc = b4[o];
            #pragma unroll
            for (int k = 0; k < 5; ++k)
                #pragma unroll
                for (int ci = 0; ci < HD; ++ci)
                    acc = fmaf(s3[ci * 13 + 2 * ll + k], sw4[(k * HD + ci) * HD + o], acc);
            ws_h4[(b * HD + o) * L4 + 5 * t + ll] = acc;
        }
    }

    grid.sync();

    // ---------------- Phase 3: tail ----------------
    if (blockIdx.x < NB) {
        float* red = smem;          // 250
        float* hm  = smem + 250;    // 10
        float* lg  = smem + 260;    // 32
        float* ltt = smem + 292;    // 32
        const int b = blockIdx.x;

        __syncthreads();
        if (tid < HD * 25) {
            const int o = tid / 25, j = tid % 25;
            const float* p = ws_h4 + (b * HD + o) * L4 + j * 5;
            red[tid] = p[0] + p[1] + p[2] + p[3] + p[4];
        }
        __syncthreads();
        if (tid < HD) {
            float s = 0.0f;
            #pragma unroll
            for (int j = 0; j < 25; ++j) s += red[tid * 25 + j];
            hm[tid] = s * (1.0f / (float)L4);
        }
        __syncthreads();
        if (tid < CH * NM) {
            float acc = bl[tid];
            #pragma unroll
            for (int k = 0; k < HD; ++k) acc = fmaf(wl[tid * HD + k], hm[k], acc);
            lg[tid] = acc;
        }
        __syncthreads();
        if (tid < CH) {
            float lv[NM];
            #pragma unroll
            for (int m = 0; m < NM; ++m) lv[m] = lg[tid * NM + m];
            const float m0 = fmaxf(fmaxf(lv[0], lv[1]), fmaxf(lv[2], lv[3]));
            float e[NM], s = 0.0f;
            #pragma unroll
            for (int m = 0; m < NM; ++m) {
                const float v = (lv[m] - m0) / 0.1f;
                ltt[tid * NM + m] = v;
                e[m] = __expf(v);
                s += e[m];
            }
            #pragma unroll
            for (int m = 0; m < NM; ++m)
                out_mw[(b * CH + tid) * NM + m] = e[m] / s;
        }
        __syncthreads();
        if (tid < NS * CH) {
            const int c = tid % CH, sI = tid / CH;
            const float* up = unif + ((b * NS + sI) * CH + c) * NM;
            float hh[NM], mx = -1e30f;
            #pragma unroll
            for (int m = 0; m < NM; ++m) {
                const float gu = -__logf(-__logf(up[m] + 1e-8f));
                hh[m] = (gu + ltt[c * NM + m]) / 0.1f;
                mx = fmaxf(mx, hh[m]);
            }
            float e2[NM], ss = 0.0f;
            #pragma unroll
            for (int m = 0; m < NM; ++m) { e2[m] = __expf(hh[m] - mx); ss += e2[m]; }
            #pragma unroll
            for (int m = 0; m < NM; ++m) {
                float y = e2[m] / ss;
                y = fminf(fmaxf(y, 1e-8f), 1.0f - 1e-8f);
                out_ms[((b * NS + sI) * CH + c) * NM + m] = y;
            }
        }
    }
}

// ================= fallback kernels (R7-proven 3-kernel path) =================
__global__ __launch_bounds__(256) void k_density(
    const float* __restrict__ xc, const float* __restrict__ yc,
    const float* __restrict__ xg, const float* __restrict__ logls,
    float* __restrict__ out_den, float* __restrict__ out_rep)
{
    __shared__ __align__(16) float sx[CH * CPAD];
    __shared__ __align__(16) float sy[CH * CPAD];
    const int b   = blockIdx.x >> 6;
    const int gt  = blockIdx.x & 63;
    const int tid = threadIdx.x;

    const float* xcb = xc + b * C * CH;
    const float* ycb = yc + b * C * CH;
    for (int i = tid; i < C * CH; i += 256) {
        const int c = i >> 3, H = i & 7;
        sx[H * CPAD + c] = xcb[i];
        sy[H * CPAD + c] = ycb[i];
    }
    __syncthreads();

    const int H  = tid & 7;
    const int gl = tid >> 3;
    const int g  = gt * 32 + gl;
    const float x = xg[(b * G + g) * CH + H];
    const float coef = -0.72134752044448170f * __expf(-2.0f * logls[H]);
    const float4* sxv = (const float4*)(sx + H * CPAD);
    const float4* syv = (const float4*)(sy + H * CPAD);

    float den = 0.0f, num = 0.0f;
    #pragma unroll 4
    for (int c4 = 0; c4 < C / 4; ++c4) {
        const float4 xv = sxv[c4];
        const float4 yv = syv[c4];
        #define STEP(XX, YY)                              \
        {                                                 \
            const float d = x - (XX);                     \
            const float w = exp2f((d * coef) * d);        \
            den += w; num = fmaf(w, (YY), num);           \
        }
        STEP(xv.x, yv.x) STEP(xv.y, yv.y) STEP(xv.z, yv.z) STEP(xv.w, yv.w)
        #undef STEP
    }
    const int o = (b * G + g) * CH + H;
    out_den[o] = den;
    out_rep[o] = num / (den + 1e-4f);
}

__global__ __launch_bounds__(256) void k_convnet(
    const float* __restrict__ rep,
    const float* __restrict__ w1, const float* __restrict__ b1,
    const float* __restrict__ w2, const float* __restrict__ b2,
    const float* __restrict__ w3, const float* __restrict__ b3,
    const float* __restrict__ w4, const float* __restrict__ b4,
    float* __restrict__ h4out)
{
    const int b   = blockIdx.x / 25;
    const int t   = blockIdx.x % 25;
    const int tid = threadIdx.x;

    __shared__ float sxt[CH * 125];
    __shared__ float sw1[5 * CH * HD];
    __shared__ float sw2[5 * HD * HD];
    __shared__ float sw3[5 * HD * HD];
    __shared__ float sw4[5 * HD * HD];
    __shared__ float s1[HD * 61];
    __shared__ float s2[HD * 29];
    __shared__ float s3[HD * 13];

    {
        const float* src = rep + (b * G + 80 * t) * CH;
        for (int i = tid; i < 125 * CH; i += 256) {
            const int gl = i >> 3, ci = i & 7;
            sxt[ci * 125 + gl] = src[i];
        }
    }
    for (int i = tid; i < HD * CH * 5; i += 256) {
        const int o = i / 40, ci = (i / 5) % 8, k = i % 5;
        sw1[(k * CH + ci) * HD + o] = w1[i];
    }
    for (int i = tid; i < HD * HD * 5; i += 256) {
        const int o = i / 50, ci = (i / 5) % 10, k = i % 5;
        sw2[(k * HD + ci) * HD + o] = w2[i];
        sw3[(k * HD + ci) * HD + o] = w3[i];
        sw4[(k * HD + ci) * HD + o] = w4[i];
    }
    __syncthreads();

    for (int i = tid; i < 61 * HD; i += 256) {
        const int o = i % HD, ll = i / HD;
        float acc = b1[o];
        #pragma unroll
        for (int k = 0; k < 5; ++k)
            #pragma unroll
            for (int ci = 0; ci < CH; ++ci)
                acc = fmaf(sxt[ci * 125 + 2 * ll + k], sw1[(k * CH + ci) * HD + o], acc);
        s1[o * 61 + ll] = fmaxf(acc, 0.0f);
    }
    __syncthreads();
    for (int i = tid; i < 29 * HD; i += 256) {
        const int o = i % HD, ll = i / HD;
        float acc = b2[o];
        #pragma unroll
        for (int k = 0; k < 5; ++k)
            #pragma unroll
            for (int ci = 0; ci < HD; ++ci)
                acc = fmaf(s1[ci * 61 + 2 * ll + k], sw2[(k * HD + ci) * HD + o], acc);
        s2[o * 29 + ll] = fmaxf(acc, 0.0f);
    }
    __syncthreads();
    for (int i = tid; i < 13 * HD; i += 256) {
        const int o = i % HD, ll = i / HD;
        float acc = b3[o];
        #pragma unroll
        for (int k = 0; k < 5; ++k)
            #pragma unroll
            for (int ci = 0; ci < HD; ++ci)
                acc = fmaf(s2[ci * 29 + 2 * ll + k], sw3[(k * HD + ci) * HD + o], acc);
        s3[o * 13 + ll] = fmaxf(acc, 0.0f);
    }
    __syncthreads();
    for (int i = tid; i < 5 * HD; i += 256) {
        const int o = i % HD, ll = i / HD;
        float acc = b4[o];
        #pragma unroll
        for (int k = 0; k < 5; ++k)
            #pragma unroll
            for (int ci = 0; ci < HD; ++ci)
                acc = fmaf(s3[ci * 13 + 2 * ll + k], sw4[(k * HD + ci) * HD + o], acc);
        h4out[(b * HD + o) * L4 + 5 * t + ll] = acc;
    }
}

__global__ __launch_bounds__(256) void k_tail(
    const float* __restrict__ h4,
    const float* __restrict__ wl, const float* __restrict__ bl,
    const float* __restrict__ unif,
    float* __restrict__ out_mw, float* __restrict__ out_ms)
{
    const int b   = blockIdx.x;
    const int tid = threadIdx.x;
    __shared__ float red[HD * 25];
    __shared__ float hm[HD];
    __shared__ float lg[CH * NM];
    __shared__ float ltt[CH * NM];

    if (tid < HD * 25) {
        const int o = tid / 25, j = tid % 25;
        const float* p = h4 + (b * HD + o) * L4 + j * 5;
        red[tid] = p[0] + p[1] + p[2] + p[3] + p[4];
    }
    __syncthreads();
    if (tid < HD) {
        float s = 0.0f;
        #pragma unroll
        for (int j = 0; j < 25; ++j) s += red[tid * 25 + j];
        hm[tid] = s * (1.0f / (float)L4);
    }
    __syncthreads();
    if (tid < CH * NM) {
        float acc = bl[tid];
        #pragma unroll
        for (int k = 0; k < HD; ++k) acc = fmaf(wl[tid * HD + k], hm[k], acc);
        lg[tid] = acc;
    }
    __syncthreads();
    if (tid < CH) {
        float lv[NM];
        #pragma unroll
        for (int m = 0; m < NM; ++m) lv[m] = lg[tid * NM + m];
        const float m0 = fmaxf(fmaxf(lv[0], lv[1]), fmaxf(lv[2], lv[3]));
        float e[NM], s = 0.0f;
        #pragma unroll
        for (int m = 0; m < NM; ++m) {
            const float v = (lv[m] - m0) / 0.1f;
            ltt[tid * NM + m] = v;
            e[m] = __expf(v);
            s += e[m];
        }
        #pragma unroll
        for (int m = 0; m < NM; ++m)
            out_mw[(b * CH + tid) * NM + m] = e[m] / s;
    }
    __syncthreads();
    if (tid < NS * CH) {
        const int c = tid % CH, sI = tid / CH;
        const float* up = unif + ((b * NS + sI) * CH + c) * NM;
        float hh[NM], mx = -1e30f;
        #pragma unroll
        for (int m = 0; m < NM; ++m) {
            const float gu = -__logf(-__logf(up[m] + 1e-8f));
            hh[m] = (gu + ltt[c * NM + m]) / 0.1f;
            mx = fmaxf(mx, hh[m]);
        }
        float e2[NM], ss = 0.0f;
        #pragma unroll
        for (int m = 0; m < NM; ++m) { e2[m] = __expf(hh[m] - mx); ss += e2[m]; }
        #pragma unroll
        for (int m = 0; m < NM; ++m) {
            float y = e2[m] / ss;
            y = fminf(fmaxf(y, 1e-8f), 1.0f - 1e-8f);
            out_ms[((b * NS + sI) * CH + c) * NM + m] = y;
        }
    }
}

extern "C" void kernel_launch(void* const* d_in, const int* in_sizes, int n_in,
                              void* d_out, int out_size, void* d_ws, size_t ws_size,
                              hipStream_t stream) {
    const float* xc    = (const float*)d_in[0];
    const float* yc    = (const float*)d_in[1];
    const float* xg    = (const float*)d_in[2];
    const float* logls = (const float*)d_in[3];
    const float* w1    = (const float*)d_in[4];
    const float* b1    = (const float*)d_in[5];
    const float* w2    = (const float*)d_in[6];
    const float* b2    = (const float*)d_in[7];
    const float* w3    = (const float*)d_in[8];
    const float* b3    = (const float*)d_in[9];
    const float* w4    = (const float*)d_in[10];
    const float* b4    = (const float*)d_in[11];
    const float* wl    = (const float*)d_in[12];
    const float* bl    = (const float*)d_in[13];
    const float* unif  = (const float*)d_in[14];

    float* out = (float*)d_out;
    float* out_den = out;
    float* out_rep = out + NB * G * CH;
    float* out_mw  = out + 2 * NB * G * CH;
    float* out_ms  = out_mw + NB * CH * NM;
    float* ws_h4   = (float*)d_ws;   // NB*HD*L4 = 10000 f32
    (void)out_size; (void)in_sizes; (void)n_in; (void)ws_size;

    void* args[] = {
        (void*)&xc, (void*)&yc, (void*)&xg, (void*)&logls,
        (void*)&w1, (void*)&b1, (void*)&w2, (void*)&b2,
        (void*)&w3, (void*)&b3, (void*)&w4, (void*)&b4,
        (void*)&wl, (void*)&bl, (void*)&unif,
        (void*)&out_den, (void*)&out_rep, (void*)&out_mw, (void*)&out_ms,
        (void*)&ws_h4
    };
    hipError_t err = hipLaunchCooperativeKernel((const void*)k_fused,
                                                dim3(NB * 64), dim3(256),
                                                args, 0, stream);
    if (err != hipSuccess) {
        // fallback: proven 3-kernel path
        k_density<<<NB * 64, 256, 0, stream>>>(xc, yc, xg, logls, out_den, out_rep);
        k_convnet<<<NB * 25, 256, 0, stream>>>(out_rep, w1, b1, w2, b2, w3, b3, w4, b4, ws_h4);
        k_tail<<<NB, 256, 0, stream>>>(ws_h4, wl, bl, unif, out_mw, out_ms);
    }
}

// Round 9
// 39.130 us; speedup vs baseline: 3.1406x; 3.1406x over previous
//
#include <hip/hip_runtime.h>
#include <hip/hip_bf16.h>

// Problem constants (fixed by setup_inputs)
#define NB 8
#define G  2048
#define C  512
#define CH 8
#define NM 4
#define HD 10
#define NS 10
#define L1 1022
#define L2 509
#define L3 253
#define L4 125

// ---------------- Kernel 1: RBF density + datarepr, scalar-broadcast form ------
// 512 blocks x 256 threads = 2048 waves. Wave = (b, H, g-tile of 64).
// xc/yc/logls addresses are wave-uniform (readfirstlane) -> scalar loads on the
// scalar pipe; inner loop is pure VALU (sub, mul, exp2, add, fma). No LDS.
__global__ __launch_bounds__(256) void k_density(
    const float* __restrict__ xc, const float* __restrict__ yc,
    const float* __restrict__ xg, const float* __restrict__ logls,
    float* __restrict__ out_den,   // (nb,G,ch)
    float* __restrict__ out_rep)   // (nb,G,ch)
{
    const int tid  = threadIdx.x;
    const int wave = tid >> 6;
    const int lane = tid & 63;
    const int W  = blockIdx.x * 4 + wave;        // 0..2047 = ((b*8+H)*32+gt)
    const int gt = W & 31;
    const int H  = __builtin_amdgcn_readfirstlane((W >> 5) & 7);
    const int b  = __builtin_amdgcn_readfirstlane(W >> 8);

    const float* xcb = xc + b * (C * CH) + H;    // stride CH between c's
    const float* ycb = yc + b * (C * CH) + H;

    const int g = gt * 64 + lane;
    const float x = xg[(b * G + g) * CH + H];
    // exp(-0.5 d^2/ls^2) == exp2( (-0.5*log2e/ls^2) * d^2 )
    const float coef = -0.72134752044448170f * __expf(-2.0f * logls[H]);

    float den = 0.0f, num = 0.0f;
    #pragma unroll 8
    for (int c = 0; c < C; ++c) {
        const float xx = xcb[c * CH];            // wave-uniform -> s_load
        const float yy = ycb[c * CH];            // wave-uniform -> s_load
        const float d = x - xx;
        const float w = exp2f((d * coef) * d);
        den += w;
        num = fmaf(w, yy, num);
    }

    const int o = (b * G + g) * CH + H;
    out_den[o] = den;
    out_rep[o] = num / (den + 1e-4f);
}

// ---------------- Kernel 2: full conv1..4 stencil chain, tiled with halo -------
// grid = NB*25 blocks x 256 threads. Tile t covers l4 in [5t,5t+5), needing
// l3 [10t,10t+13), l2 [20t,20t+29), l1 [40t,40t+61), g [80t,80t+125).
__global__ __launch_bounds__(256) void k_convnet(
    const float* __restrict__ rep,
    const float* __restrict__ w1, const float* __restrict__ b1,
    const float* __restrict__ w2, const float* __restrict__ b2,
    const float* __restrict__ w3, const float* __restrict__ b3,
    const float* __restrict__ w4, const float* __restrict__ b4,
    float* __restrict__ h4out)   // (NB, HD, L4)
{
    const int b   = blockIdx.x / 25;
    const int t   = blockIdx.x % 25;
    const int tid = threadIdx.x;

    __shared__ float sxt[CH * 125];      // rep tile, [ci][125]
    __shared__ float sw1[5 * CH * HD];   // [k][ci][o]
    __shared__ float sw2[5 * HD * HD];
    __shared__ float sw3[5 * HD * HD];
    __shared__ float sw4[5 * HD * HD];
    __shared__ float s1[HD * 61];        // [ci][61]
    __shared__ float s2[HD * 29];
    __shared__ float s3[HD * 13];

    {
        const float* src = rep + (b * G + 80 * t) * CH;
        for (int i = tid; i < 125 * CH; i += 256) {
            const int gl = i >> 3, ci = i & 7;
            sxt[ci * 125 + gl] = src[i];
        }
    }
    for (int i = tid; i < HD * CH * 5; i += 256) {
        const int o = i / 40, ci = (i / 5) % 8, k = i % 5;
        sw1[(k * CH + ci) * HD + o] = w1[i];
    }
    for (int i = tid; i < HD * HD * 5; i += 256) {
        const int o = i / 50, ci = (i / 5) % 10, k = i % 5;
        sw2[(k * HD + ci) * HD + o] = w2[i];
        sw3[(k * HD + ci) * HD + o] = w3[i];
        sw4[(k * HD + ci) * HD + o] = w4[i];
    }
    __syncthreads();

    for (int i = tid; i < 61 * HD; i += 256) {
        const int o = i % HD, ll = i / HD;
        float acc = b1[o];
        #pragma unroll
        for (int k = 0; k < 5; ++k)
            #pragma unroll
            for (int ci = 0; ci < CH; ++ci)
                acc = fmaf(sxt[ci * 125 + 2 * ll + k], sw1[(k * CH + ci) * HD + o], acc);
        s1[o * 61 + ll] = fmaxf(acc, 0.0f);
    }
    __syncthreads();

    for (int i = tid; i < 29 * HD; i += 256) {
        const int o = i % HD, ll = i / HD;
        float acc = b2[o];
        #pragma unroll
        for (int k = 0; k < 5; ++k)
            #pragma unroll
            for (int ci = 0; ci < HD; ++ci)
                acc = fmaf(s1[ci * 61 + 2 * ll + k], sw2[(k * HD + ci) * HD + o], acc);
        s2[o * 29 + ll] = fmaxf(acc, 0.0f);
    }
    __syncthreads();

    for (int i = tid; i < 13 * HD; i += 256) {
        const int o = i % HD, ll = i / HD;
        float acc = b3[o];
        #pragma unroll
        for (int k = 0; k < 5; ++k)
            #pragma unroll
            for (int ci = 0; ci < HD; ++ci)
                acc = fmaf(s2[ci * 29 + 2 * ll + k], sw3[(k * HD + ci) * HD + o], acc);
        s3[o * 13 + ll] = fmaxf(acc, 0.0f);
    }
    __syncthreads();

    for (int i = tid; i < 5 * HD; i += 256) {
        const int o = i % HD, ll = i / HD;
        float acc = b4[o];
        #pragma unroll
        for (int k = 0; k < 5; ++k)
            #pragma unroll
            for (int ci = 0; ci < HD; ++ci)
                acc = fmaf(s3[ci * 13 + 2 * ll + k], sw4[(k * HD + ci) * HD + o], acc);
        h4out[(b * HD + o) * L4 + 5 * t + ll] = acc;
    }
}

// ---------------- Kernel 3: pool + linear + softmax + gumbel ----------------
__global__ __launch_bounds__(256) void k_tail(
    const float* __restrict__ h4,   // (NB, HD, L4)
    const float* __restrict__ wl, const float* __restrict__ bl,
    const float* __restrict__ unif,
    float* __restrict__ out_mw,   // (NB, CH, NM)
    float* __restrict__ out_ms)   // (NB, NS, CH, NM)
{
    const int b   = blockIdx.x;
    const int tid = threadIdx.x;
    __shared__ float red[HD * 25];
    __shared__ float hm[HD];
    __shared__ float lg[CH * NM];
    __shared__ float ltt[CH * NM];

    if (tid < HD * 25) {
        const int o = tid / 25, j = tid % 25;
        const float* p = h4 + (b * HD + o) * L4 + j * 5;
        red[tid] = p[0] + p[1] + p[2] + p[3] + p[4];
    }
    __syncthreads();
    if (tid < HD) {
        float s = 0.0f;
        #pragma unroll
        for (int j = 0; j < 25; ++j) s += red[tid * 25 + j];
        hm[tid] = s * (1.0f / (float)L4);
    }
    __syncthreads();
    if (tid < CH * NM) {
        float acc = bl[tid];
        #pragma unroll
        for (int k = 0; k < HD; ++k) acc = fmaf(wl[tid * HD + k], hm[k], acc);
        lg[tid] = acc;
    }
    __syncthreads();
    if (tid < CH) {
        float lv[NM];
        #pragma unroll
        for (int m = 0; m < NM; ++m) lv[m] = lg[tid * NM + m];
        const float m0 = fmaxf(fmaxf(lv[0], lv[1]), fmaxf(lv[2], lv[3]));
        float e[NM], s = 0.0f;
        #pragma unroll
        for (int m = 0; m < NM; ++m) {
            const float v = (lv[m] - m0) / 0.1f;
            ltt[tid * NM + m] = v;
            e[m] = __expf(v);
            s += e[m];
        }
        #pragma unroll
        for (int m = 0; m < NM; ++m)
            out_mw[(b * CH + tid) * NM + m] = e[m] / s;
    }
    __syncthreads();
    if (tid < NS * CH) {
        const int c = tid % CH, sI = tid / CH;
        const float* up = unif + ((b * NS + sI) * CH + c) * NM;
        float hh[NM], mx = -1e30f;
        #pragma unroll
        for (int m = 0; m < NM; ++m) {
            const float gu = -__logf(-__logf(up[m] + 1e-8f));
            hh[m] = (gu + ltt[c * NM + m]) / 0.1f;
            mx = fmaxf(mx, hh[m]);
        }
        float e2[NM], ss = 0.0f;
        #pragma unroll
        for (int m = 0; m < NM; ++m) { e2[m] = __expf(hh[m] - mx); ss += e2[m]; }
        #pragma unroll
        for (int m = 0; m < NM; ++m) {
            float y = e2[m] / ss;
            y = fminf(fmaxf(y, 1e-8f), 1.0f - 1e-8f);
            out_ms[((b * NS + sI) * CH + c) * NM + m] = y;
        }
    }
}

extern "C" void kernel_launch(void* const* d_in, const int* in_sizes, int n_in,
                              void* d_out, int out_size, void* d_ws, size_t ws_size,
                              hipStream_t stream) {
    const float* xc    = (const float*)d_in[0];
    const float* yc    = (const float*)d_in[1];
    const float* xg    = (const float*)d_in[2];
    const float* logls = (const float*)d_in[3];
    const float* w1    = (const float*)d_in[4];
    const float* b1    = (const float*)d_in[5];
    const float* w2    = (const float*)d_in[6];
    const float* b2    = (const float*)d_in[7];
    const float* w3    = (const float*)d_in[8];
    const float* b3    = (const float*)d_in[9];
    const float* w4    = (const float*)d_in[10];
    const float* b4    = (const float*)d_in[11];
    const float* wl    = (const float*)d_in[12];
    const float* bl    = (const float*)d_in[13];
    const float* unif  = (const float*)d_in[14];

    float* out = (float*)d_out;                 // reference outputs are float32
    float* out_den = out;                       // 131072
    float* out_rep = out + NB * G * CH;         // 131072
    float* out_mw  = out + 2 * NB * G * CH;     // 256
    float* out_ms  = out_mw + NB * CH * NM;     // 2560
    (void)out_size; (void)in_sizes; (void)n_in; (void)ws_size;

    float* ws_h4 = (float*)d_ws;                // NB*HD*L4 = 10000 f32 (40 KB)

    k_density<<<512, 256, 0, stream>>>(xc, yc, xg, logls, out_den, out_rep);

    k_convnet<<<NB * 25, 256, 0, stream>>>(out_rep, w1, b1, w2, b2, w3, b3, w4, b4,
                                           ws_h4);

    k_tail<<<NB, 256, 0, stream>>>(ws_h4, wl, bl, unif, out_mw, out_ms);
}

// Round 10
// 35.446 us; speedup vs baseline: 3.4671x; 1.1039x over previous
//
#include <hip/hip_runtime.h>
#include <hip/hip_bf16.h>

// Problem constants (fixed by setup_inputs)
#define NB 8
#define G  2048
#define C  512
#define CH 8
#define NM 4
#define HD 10
#define NS 10
#define L1 1022
#define L2 509
#define L3 253
#define L4 125

// ---------------- Kernel 1a: density partial sums over c-chunks ----------------
// 2048 blocks x 256 threads = 8192 waves (32 waves/CU). Wave = (cchunk, b, H, gt).
// xc/yc addresses wave-uniform -> scalar loads; inner loop VALU + native v_exp.
__global__ __launch_bounds__(256) void k_density_part(
    const float* __restrict__ xc, const float* __restrict__ yc,
    const float* __restrict__ xg, const float* __restrict__ logls,
    float* __restrict__ pd,   // (4, NB, CH, G) partial density
    float* __restrict__ pn)   // (4, NB, CH, G) partial numerator
{
    const int tid  = threadIdx.x;
    const int wave = tid >> 6;
    const int lane = tid & 63;
    const int W  = blockIdx.x * 4 + wave;        // 0..8191
    const int cchunk = W & 3;
    const int id = W >> 2;                       // 0..2047 = ((b*8+H)*32+gt)
    const int gt = id & 31;
    const int H  = __builtin_amdgcn_readfirstlane((id >> 5) & 7);
    const int b  = __builtin_amdgcn_readfirstlane(id >> 8);

    const int g = gt * 64 + lane;
    const float x = xg[(b * G + g) * CH + H];
    // exp(-0.5 d^2/ls^2) == exp2( (-0.5*log2e/ls^2) * d^2 )
    const float coef = -0.72134752044448170f * __expf(-2.0f * logls[H]);

    const float* xcb = xc + (b * C + cchunk * 128) * CH + H;   // stride CH per c
    const float* ycb = yc + (b * C + cchunk * 128) * CH + H;

    float den = 0.0f, num = 0.0f;
    #pragma unroll 8
    for (int c = 0; c < 128; ++c) {
        const float xx = xcb[c * CH];            // wave-uniform -> s_load
        const float yy = ycb[c * CH];
        const float d = x - xx;
        const float w = __builtin_amdgcn_exp2f((d * coef) * d);  // single v_exp_f32
        den += w;
        num = fmaf(w, yy, num);
    }

    const int p = ((cchunk * NB + b) * CH + H) * G + g;   // g contiguous per wave
    pd[p] = den;
    pn[p] = num;
}

// ---------------- Kernel 1b: reduce 4 partials -> den, rep ----------------
// 512 blocks x 256 threads; thread = (b, H, g) in partial layout (coalesced reads).
__global__ __launch_bounds__(256) void k_density_reduce(
    const float* __restrict__ pd, const float* __restrict__ pn,
    float* __restrict__ out_den,   // (nb,G,ch)
    float* __restrict__ out_rep)   // (nb,G,ch)
{
    const int id = blockIdx.x * 256 + threadIdx.x;   // 0..131071
    const int g  = id & (G - 1);
    const int H  = (id >> 11) & 7;
    const int b  = id >> 14;

    float den = 0.0f, num = 0.0f;
    #pragma unroll
    for (int cc = 0; cc < 4; ++cc) {
        const int p = ((cc * NB + b) * CH + H) * G + g;
        den += pd[p];
        num += pn[p];
    }
    const int o = (b * G + g) * CH + H;
    out_den[o] = den;
    out_rep[o] = num / (den + 1e-4f);
}

// ---------------- Kernel 2: full conv1..4 stencil chain, tiled with halo -------
// grid = NB*25 blocks x 256 threads. Tile t covers l4 in [5t,5t+5), needing
// l3 [10t,10t+13), l2 [20t,20t+29), l1 [40t,40t+61), g [80t,80t+125).
__global__ __launch_bounds__(256) void k_convnet(
    const float* __restrict__ rep,
    const float* __restrict__ w1, const float* __restrict__ b1,
    const float* __restrict__ w2, const float* __restrict__ b2,
    const float* __restrict__ w3, const float* __restrict__ b3,
    const float* __restrict__ w4, const float* __restrict__ b4,
    float* __restrict__ h4out)   // (NB, HD, L4)
{
    const int b   = blockIdx.x / 25;
    const int t   = blockIdx.x % 25;
    const int tid = threadIdx.x;

    __shared__ float sxt[CH * 125];      // rep tile, [ci][125]
    __shared__ float sw1[5 * CH * HD];   // [k][ci][o]
    __shared__ float sw2[5 * HD * HD];
    __shared__ float sw3[5 * HD * HD];
    __shared__ float sw4[5 * HD * HD];
    __shared__ float s1[HD * 61];        // [ci][61]
    __shared__ float s2[HD * 29];
    __shared__ float s3[HD * 13];

    {
        const float* src = rep + (b * G + 80 * t) * CH;
        for (int i = tid; i < 125 * CH; i += 256) {
            const int gl = i >> 3, ci = i & 7;
            sxt[ci * 125 + gl] = src[i];
        }
    }
    for (int i = tid; i < HD * CH * 5; i += 256) {
        const int o = i / 40, ci = (i / 5) % 8, k = i % 5;
        sw1[(k * CH + ci) * HD + o] = w1[i];
    }
    for (int i = tid; i < HD * HD * 5; i += 256) {
        const int o = i / 50, ci = (i / 5) % 10, k = i % 5;
        sw2[(k * HD + ci) * HD + o] = w2[i];
        sw3[(k * HD + ci) * HD + o] = w3[i];
        sw4[(k * HD + ci) * HD + o] = w4[i];
    }
    __syncthreads();

    for (int i = tid; i < 61 * HD; i += 256) {
        const int o = i % HD, ll = i / HD;
        float acc = b1[o];
        #pragma unroll
        for (int k = 0; k < 5; ++k)
            #pragma unroll
            for (int ci = 0; ci < CH; ++ci)
                acc = fmaf(sxt[ci * 125 + 2 * ll + k], sw1[(k * CH + ci) * HD + o], acc);
        s1[o * 61 + ll] = fmaxf(acc, 0.0f);
    }
    __syncthreads();

    for (int i = tid; i < 29 * HD; i += 256) {
        const int o = i % HD, ll = i / HD;
        float acc = b2[o];
        #pragma unroll
        for (int k = 0; k < 5; ++k)
            #pragma unroll
            for (int ci = 0; ci < HD; ++ci)
                acc = fmaf(s1[ci * 61 + 2 * ll + k], sw2[(k * HD + ci) * HD + o], acc);
        s2[o * 29 + ll] = fmaxf(acc, 0.0f);
    }
    __syncthreads();

    for (int i = tid; i < 13 * HD; i += 256) {
        const int o = i % HD, ll = i / HD;
        float acc = b3[o];
        #pragma unroll
        for (int k = 0; k < 5; ++k)
            #pragma unroll
            for (int ci = 0; ci < HD; ++ci)
                acc = fmaf(s2[ci * 29 + 2 * ll + k], sw3[(k * HD + ci) * HD + o], acc);
        s3[o * 13 + ll] = fmaxf(acc, 0.0f);
    }
    __syncthreads();

    for (int i = tid; i < 5 * HD; i += 256) {
        const int o = i % HD, ll = i / HD;
        float acc = b4[o];
        #pragma unroll
        for (int k = 0; k < 5; ++k)
            #pragma unroll
            for (int ci = 0; ci < HD; ++ci)
                acc = fmaf(s3[ci * 13 + 2 * ll + k], sw4[(k * HD + ci) * HD + o], acc);
        h4out[(b * HD + o) * L4 + 5 * t + ll] = acc;
    }
}

// ---------------- Kernel 3: pool + linear + softmax + gumbel ----------------
__global__ __launch_bounds__(256) void k_tail(
    const float* __restrict__ h4,   // (NB, HD, L4)
    const float* __restrict__ wl, const float* __restrict__ bl,
    const float* __restrict__ unif,
    float* __restrict__ out_mw,   // (NB, CH, NM)
    float* __restrict__ out_ms)   // (NB, NS, CH, NM)
{
    const int b   = blockIdx.x;
    const int tid = threadIdx.x;
    __shared__ float red[HD * 25];
    __shared__ float hm[HD];
    __shared__ float lg[CH * NM];
    __shared__ float ltt[CH * NM];

    if (tid < HD * 25) {
        const int o = tid / 25, j = tid % 25;
        const float* p = h4 + (b * HD + o) * L4 + j * 5;
        red[tid] = p[0] + p[1] + p[2] + p[3] + p[4];
    }
    __syncthreads();
    if (tid < HD) {
        float s = 0.0f;
        #pragma unroll
        for (int j = 0; j < 25; ++j) s += red[tid * 25 + j];
        hm[tid] = s * (1.0f / (float)L4);
    }
    __syncthreads();
    if (tid < CH * NM) {
        float acc = bl[tid];
        #pragma unroll
        for (int k = 0; k < HD; ++k) acc = fmaf(wl[tid * HD + k], hm[k], acc);
        lg[tid] = acc;
    }
    __syncthreads();
    if (tid < CH) {
        float lv[NM];
        #pragma unroll
        for (int m = 0; m < NM; ++m) lv[m] = lg[tid * NM + m];
        const float m0 = fmaxf(fmaxf(lv[0], lv[1]), fmaxf(lv[2], lv[3]));
        float e[NM], s = 0.0f;
        #pragma unroll
        for (int m = 0; m < NM; ++m) {
            const float v = (lv[m] - m0) / 0.1f;
            ltt[tid * NM + m] = v;
            e[m] = __expf(v);
            s += e[m];
        }
        #pragma unroll
        for (int m = 0; m < NM; ++m)
            out_mw[(b * CH + tid) * NM + m] = e[m] / s;
    }
    __syncthreads();
    if (tid < NS * CH) {
        const int c = tid % CH, sI = tid / CH;
        const float* up = unif + ((b * NS + sI) * CH + c) * NM;
        float hh[NM], mx = -1e30f;
        #pragma unroll
        for (int m = 0; m < NM; ++m) {
            const float gu = -__logf(-__logf(up[m] + 1e-8f));
            hh[m] = (gu + ltt[c * NM + m]) / 0.1f;
            mx = fmaxf(mx, hh[m]);
        }
        float e2[NM], ss = 0.0f;
        #pragma unroll
        for (int m = 0; m < NM; ++m) { e2[m] = __expf(hh[m] - mx); ss += e2[m]; }
        #pragma unroll
        for (int m = 0; m < NM; ++m) {
            float y = e2[m] / ss;
            y = fminf(fmaxf(y, 1e-8f), 1.0f - 1e-8f);
            out_ms[((b * NS + sI) * CH + c) * NM + m] = y;
        }
    }
}

extern "C" void kernel_launch(void* const* d_in, const int* in_sizes, int n_in,
                              void* d_out, int out_size, void* d_ws, size_t ws_size,
                              hipStream_t stream) {
    const float* xc    = (const float*)d_in[0];
    const float* yc    = (const float*)d_in[1];
    const float* xg    = (const float*)d_in[2];
    const float* logls = (const float*)d_in[3];
    const float* w1    = (const float*)d_in[4];
    const float* b1    = (const float*)d_in[5];
    const float* w2    = (const float*)d_in[6];
    const float* b2    = (const float*)d_in[7];
    const float* w3    = (const float*)d_in[8];
    const float* b3    = (const float*)d_in[9];
    const float* w4    = (const float*)d_in[10];
    const float* b4    = (const float*)d_in[11];
    const float* wl    = (const float*)d_in[12];
    const float* bl    = (const float*)d_in[13];
    const float* unif  = (const float*)d_in[14];

    float* out = (float*)d_out;                 // reference outputs are float32
    float* out_den = out;                       // 131072
    float* out_rep = out + NB * G * CH;         // 131072
    float* out_mw  = out + 2 * NB * G * CH;     // 256
    float* out_ms  = out_mw + NB * CH * NM;     // 2560
    (void)out_size; (void)in_sizes; (void)n_in; (void)ws_size;

    float* pd    = (float*)d_ws;                // 4*131072 f32
    float* pn    = pd + 4 * NB * G * CH;        // 4*131072 f32
    float* ws_h4 = pn + 4 * NB * G * CH;        // NB*HD*L4 = 10000 f32

    k_density_part<<<2048, 256, 0, stream>>>(xc, yc, xg, logls, pd, pn);

    k_density_reduce<<<512, 256, 0, stream>>>(pd, pn, out_den, out_rep);

    k_convnet<<<NB * 25, 256, 0, stream>>>(out_rep, w1, b1, w2, b2, w3, b3, w4, b4,
                                           ws_h4);

    k_tail<<<NB, 256, 0, stream>>>(ws_h4, wl, bl, unif, out_mw, out_ms);
}

// Round 11
// 31.512 us; speedup vs baseline: 3.8999x; 1.1248x over previous
//
#include <hip/hip_runtime.h>
#include <hip/hip_bf16.h>

// Problem constants (fixed by setup_inputs)
#define NB 8
#define G  2048
#define C  512
#define CH 8
#define NM 4
#define HD 10
#define NS 10
#define L1 1022
#define L2 509
#define L3 253
#define L4 125

// ---------------- Kernel 1: RBF density + datarepr, block-internal c-split -----
// 2048 blocks x 256 threads (= 8 blocks/CU, 32 waves/CU). Block = (b, H, 64 g's);
// wave w sums c-chunk [w*128, w*128+128). xc/yc addresses are wave-uniform ->
// scalar loads on the scalar pipe; inner loop is 5 VALU + 1 v_exp per c.
// Cross-wave reduce through 2 KB LDS, then wave 0 writes den/rep.
__global__ __launch_bounds__(256) void k_density(
    const float* __restrict__ xc, const float* __restrict__ yc,
    const float* __restrict__ xg, const float* __restrict__ logls,
    float* __restrict__ out_den,   // (nb,G,ch)
    float* __restrict__ out_rep)   // (nb,G,ch)
{
    __shared__ float sden[4][64];
    __shared__ float snum[4][64];
    const int tid  = threadIdx.x;
    const int wave = tid >> 6;
    const int lane = tid & 63;
    const int id = blockIdx.x;                 // 0..2047 = ((b*8+H)*32+gt)
    const int gt = id & 31;
    const int H  = (id >> 5) & 7;
    const int b  = id >> 8;

    const int g = gt * 64 + lane;
    const float x = xg[(b * G + g) * CH + H];
    // exp(-0.5 d^2/ls^2) == exp2( (-0.5*log2e/ls^2) * d^2 )
    const float coef = -0.72134752044448170f * __expf(-2.0f * logls[H]);

    const float* xcb = xc + (b * C + wave * 128) * CH + H;   // stride CH per c
    const float* ycb = yc + (b * C + wave * 128) * CH + H;

    float den = 0.0f, num = 0.0f;
    #pragma unroll 8
    for (int c = 0; c < 128; ++c) {
        const float xx = xcb[c * CH];            // wave-uniform -> s_load
        const float yy = ycb[c * CH];
        const float d = x - xx;
        const float w = __builtin_amdgcn_exp2f((d * coef) * d);
        den += w;
        num = fmaf(w, yy, num);
    }

    sden[wave][lane] = den;
    snum[wave][lane] = num;
    __syncthreads();

    if (tid < 64) {
        const float dtot = sden[0][tid] + sden[1][tid] + sden[2][tid] + sden[3][tid];
        const float ntot = snum[0][tid] + snum[1][tid] + snum[2][tid] + snum[3][tid];
        const int o = (b * G + gt * 64 + tid) * CH + H;
        out_den[o] = dtot;
        out_rep[o] = ntot / (dtot + 1e-4f);
    }
}

// ---------------- Kernel 2: full conv1..4 stencil chain, tiled with halo -------
// grid = NB*25 blocks x 256 threads. Tile t covers l4 in [5t,5t+5), needing
// l3 [10t,10t+13), l2 [20t,20t+29), l1 [40t,40t+61), g [80t,80t+125).
__global__ __launch_bounds__(256) void k_convnet(
    const float* __restrict__ rep,
    const float* __restrict__ w1, const float* __restrict__ b1,
    const float* __restrict__ w2, const float* __restrict__ b2,
    const float* __restrict__ w3, const float* __restrict__ b3,
    const float* __restrict__ w4, const float* __restrict__ b4,
    float* __restrict__ h4out)   // (NB, HD, L4)
{
    const int b   = blockIdx.x / 25;
    const int t   = blockIdx.x % 25;
    const int tid = threadIdx.x;

    __shared__ float sxt[CH * 125];      // rep tile, [ci][125]
    __shared__ float sw1[5 * CH * HD];   // [k][ci][o]
    __shared__ float sw2[5 * HD * HD];
    __shared__ float sw3[5 * HD * HD];
    __shared__ float sw4[5 * HD * HD];
    __shared__ float s1[HD * 61];        // [ci][61]
    __shared__ float s2[HD * 29];
    __shared__ float s3[HD * 13];

    {
        const float* src = rep + (b * G + 80 * t) * CH;
        for (int i = tid; i < 125 * CH; i += 256) {
            const int gl = i >> 3, ci = i & 7;
            sxt[ci * 125 + gl] = src[i];
        }
    }
    for (int i = tid; i < HD * CH * 5; i += 256) {
        const int o = i / 40, ci = (i / 5) % 8, k = i % 5;
        sw1[(k * CH + ci) * HD + o] = w1[i];
    }
    for (int i = tid; i < HD * HD * 5; i += 256) {
        const int o = i / 50, ci = (i / 5) % 10, k = i % 5;
        sw2[(k * HD + ci) * HD + o] = w2[i];
        sw3[(k * HD + ci) * HD + o] = w3[i];
        sw4[(k * HD + ci) * HD + o] = w4[i];
    }
    __syncthreads();

    for (int i = tid; i < 61 * HD; i += 256) {
        const int o = i % HD, ll = i / HD;
        float acc = b1[o];
        #pragma unroll
        for (int k = 0; k < 5; ++k)
            #pragma unroll
            for (int ci = 0; ci < CH; ++ci)
                acc = fmaf(sxt[ci * 125 + 2 * ll + k], sw1[(k * CH + ci) * HD + o], acc);
        s1[o * 61 + ll] = fmaxf(acc, 0.0f);
    }
    __syncthreads();

    for (int i = tid; i < 29 * HD; i += 256) {
        const int o = i % HD, ll = i / HD;
        float acc = b2[o];
        #pragma unroll
        for (int k = 0; k < 5; ++k)
            #pragma unroll
            for (int ci = 0; ci < HD; ++ci)
                acc = fmaf(s1[ci * 61 + 2 * ll + k], sw2[(k * HD + ci) * HD + o], acc);
        s2[o * 29 + ll] = fmaxf(acc, 0.0f);
    }
    __syncthreads();

    for (int i = tid; i < 13 * HD; i += 256) {
        const int o = i % HD, ll = i / HD;
        float acc = b3[o];
        #pragma unroll
        for (int k = 0; k < 5; ++k)
            #pragma unroll
            for (int ci = 0; ci < HD; ++ci)
                acc = fmaf(s2[ci * 29 + 2 * ll + k], sw3[(k * HD + ci) * HD + o], acc);
        s3[o * 13 + ll] = fmaxf(acc, 0.0f);
    }
    __syncthreads();

    for (int i = tid; i < 5 * HD; i += 256) {
        const int o = i % HD, ll = i / HD;
        float acc = b4[o];
        #pragma unroll
        for (int k = 0; k < 5; ++k)
            #pragma unroll
            for (int ci = 0; ci < HD; ++ci)
                acc = fmaf(s3[ci * 13 + 2 * ll + k], sw4[(k * HD + ci) * HD + o], acc);
        h4out[(b * HD + o) * L4 + 5 * t + ll] = acc;
    }
}

// ---------------- Kernel 3: pool + linear + softmax + gumbel ----------------
__global__ __launch_bounds__(256) void k_tail(
    const float* __restrict__ h4,   // (NB, HD, L4)
    const float* __restrict__ wl, const float* __restrict__ bl,
    const float* __restrict__ unif,
    float* __restrict__ out_mw,   // (NB, CH, NM)
    float* __restrict__ out_ms)   // (NB, NS, CH, NM)
{
    const int b   = blockIdx.x;
    const int tid = threadIdx.x;
    __shared__ float red[HD * 25];
    __shared__ float hm[HD];
    __shared__ float lg[CH * NM];
    __shared__ float ltt[CH * NM];

    if (tid < HD * 25) {
        const int o = tid / 25, j = tid % 25;
        const float* p = h4 + (b * HD + o) * L4 + j * 5;
        red[tid] = p[0] + p[1] + p[2] + p[3] + p[4];
    }
    __syncthreads();
    if (tid < HD) {
        float s = 0.0f;
        #pragma unroll
        for (int j = 0; j < 25; ++j) s += red[tid * 25 + j];
        hm[tid] = s * (1.0f / (float)L4);
    }
    __syncthreads();
    if (tid < CH * NM) {
        float acc = bl[tid];
        #pragma unroll
        for (int k = 0; k < HD; ++k) acc = fmaf(wl[tid * HD + k], hm[k], acc);
        lg[tid] = acc;
    }
    __syncthreads();
    if (tid < CH) {
        float lv[NM];
        #pragma unroll
        for (int m = 0; m < NM; ++m) lv[m] = lg[tid * NM + m];
        const float m0 = fmaxf(fmaxf(lv[0], lv[1]), fmaxf(lv[2], lv[3]));
        float e[NM], s = 0.0f;
        #pragma unroll
        for (int m = 0; m < NM; ++m) {
            const float v = (lv[m] - m0) / 0.1f;
            ltt[tid * NM + m] = v;
            e[m] = __expf(v);
            s += e[m];
        }
        #pragma unroll
        for (int m = 0; m < NM; ++m)
            out_mw[(b * CH + tid) * NM + m] = e[m] / s;
    }
    __syncthreads();
    if (tid < NS * CH) {
        const int c = tid % CH, sI = tid / CH;
        const float* up = unif + ((b * NS + sI) * CH + c) * NM;
        float hh[NM], mx = -1e30f;
        #pragma unroll
        for (int m = 0; m < NM; ++m) {
            const float gu = -__logf(-__logf(up[m] + 1e-8f));
            hh[m] = (gu + ltt[c * NM + m]) / 0.1f;
            mx = fmaxf(mx, hh[m]);
        }
        float e2[NM], ss = 0.0f;
        #pragma unroll
        for (int m = 0; m < NM; ++m) { e2[m] = __expf(hh[m] - mx); ss += e2[m]; }
        #pragma unroll
        for (int m = 0; m < NM; ++m) {
            float y = e2[m] / ss;
            y = fminf(fmaxf(y, 1e-8f), 1.0f - 1e-8f);
            out_ms[((b * NS + sI) * CH + c) * NM + m] = y;
        }
    }
}

extern "C" void kernel_launch(void* const* d_in, const int* in_sizes, int n_in,
                              void* d_out, int out_size, void* d_ws, size_t ws_size,
                              hipStream_t stream) {
    const float* xc    = (const float*)d_in[0];
    const float* yc    = (const float*)d_in[1];
    const float* xg    = (const float*)d_in[2];
    const float* logls = (const float*)d_in[3];
    const float* w1    = (const float*)d_in[4];
    const float* b1    = (const float*)d_in[5];
    const float* w2    = (const float*)d_in[6];
    const float* b2    = (const float*)d_in[7];
    const float* w3    = (const float*)d_in[8];
    const float* b3    = (const float*)d_in[9];
    const float* w4    = (const float*)d_in[10];
    const float* b4    = (const float*)d_in[11];
    const float* wl    = (const float*)d_in[12];
    const float* bl    = (const float*)d_in[13];
    const float* unif  = (const float*)d_in[14];

    float* out = (float*)d_out;                 // reference outputs are float32
    float* out_den = out;                       // 131072
    float* out_rep = out + NB * G * CH;         // 131072
    float* out_mw  = out + 2 * NB * G * CH;     // 256
    float* out_ms  = out_mw + NB * CH * NM;     // 2560
    (void)out_size; (void)in_sizes; (void)n_in; (void)ws_size;

    float* ws_h4 = (float*)d_ws;                // NB*HD*L4 = 10000 f32 (40 KB)

    k_density<<<2048, 256, 0, stream>>>(xc, yc, xg, logls, out_den, out_rep);

    k_convnet<<<NB * 25, 256, 0, stream>>>(out_rep, w1, b1, w2, b2, w3, b3, w4, b4,
                                           ws_h4);

    k_tail<<<NB, 256, 0, stream>>>(ws_h4, wl, bl, unif, out_mw, out_ms);
}